// Round 8
// baseline (218.524 us; speedup 1.0000x reference)
//
#include <hip/hip_runtime.h>
#include <hip/hip_bf16.h>
#include <math.h>

#define B_   128
#define Qn   30
#define Dn   200
#define En   300

typedef __attribute__((ext_vector_type(8))) short short8;
typedef __attribute__((ext_vector_type(4))) float floatx4;
typedef unsigned int u32;
typedef unsigned short u16;

typedef const __attribute__((address_space(1))) unsigned int* gas_ptr;
typedef __attribute__((address_space(3))) unsigned int* las_ptr;

static __device__ __forceinline__ void gld_lds16(const void* g, void* l) {
    __builtin_amdgcn_global_load_lds((gas_ptr)g, (las_ptr)l, 16, 0, 0);
}

static __device__ __forceinline__ u16 f2b(float x) {   // fp32 -> bf16 RNE
    union { float f; u32 u; } v; v.f = x;
    u32 r = v.u + 0x7FFFu + ((v.u >> 16) & 1u);
    return (u16)(r >> 16);
}
static __device__ __forceinline__ float bits2f(u32 u) {
    union { u32 u2; float f; } v; v.u2 = u; return v.f;
}

// ---------------------------------------------------------------------------
// prep: weight permute ONLY (R3 form). ks-major: one K-slice = 48 KB:
//   Wt3[ks 10][ g1 j0 (8 chunks) | g2 j0,j1 (16) | g3 j0..j2 (24) ] x 1KB
// ---------------------------------------------------------------------------
__global__ void prep_kernel(
    const float* __restrict__ w1, const float* __restrict__ w2, const float* __restrict__ w3,
    u16* __restrict__ Wt3)
{
    int p = (blockIdx.x*128 + blockIdx.y)*256 + threadIdx.x;
    if (p >= 245760) return;
    int ks = p / 24576;
    int r  = p - ks*24576;
    int g, rr;
    if (r < 4096)        { g = 0; rr = r;         }
    else if (r < 12288)  { g = 1; rr = r - 4096;  }
    else                 { g = 2; rr = r - 12288; }
    int j  = rr >> 12;
    int r2 = rr & 4095;
    int nt  = r2 >> 9;
    int q4  = (r2 >> 7) & 3;
    int c16 = (r2 >> 3) & 15;
    int k8  = r2 & 7;
    int ch = nt*16 + c16;
    int e  = ks*32 + q4*8 + k8;
    float v = 0.f;
    if (e < En) {
        if (g == 0)      v = w1[ch*En + e];
        else if (g == 1) v = w2[(ch*En + e)*2 + j];
        else             v = w3[(ch*En + e)*3 + j];
    }
    Wt3[p] = f2b(v);
}

// ---------------------------------------------------------------------------
// Fused conv, R8: B staged to LDS via global_load_lds (issues at program
// point, zero VGPR — the compiler cannot sink it, unlike the R3-R7
// register loads that left VGPR=44 and every load stall exposed), with the
// T3 minimum 2-phase counted-vmcnt pipeline:
//   per ks: [issue DMA for ks+1] [compute ks] [s_waitcnt vmcnt(0)] [barrier]
// The drain lands AFTER the 24-MFMA compute phase, so the DMA's L2 latency
// is hidden (R1's structure drained BEFORE compute -> 44 us).
// A gathered from emb in the prologue, overlapping the ks0 DMA.
// MFMA accumulation order per output identical => bit-identical results.
// LDS: As 43296 + toks 264 + 2 x 49152 = 141,864 B (1 block/CU).
// ---------------------------------------------------------------------------
__global__ __launch_bounds__(512, 2) void conv_kernel(
    const int* __restrict__ qtok, const int* __restrict__ dtok,
    const float* __restrict__ emb,
    const u16* __restrict__ Wt3,
    const float* __restrict__ b1, const float* __restrict__ b2, const float* __restrict__ b3,
    u16* __restrict__ qg, u16* __restrict__ dg,
    float* __restrict__ invnq, float* __restrict__ invnd)
{
    extern __shared__ char smem[];
    char* As  = smem;                       // [66][656 B]
    int*  toks = (int*)(smem + 43296);      // [66]
    char* Bs0 = smem + 43560;               // 49152
    char* Bs1 = smem + 92712;               // 49152

    const int tile = blockIdx.x;
    const int tid = threadIdx.x;
    const int wv = tid >> 6, lane = tid & 63;
    const int l15 = lane & 15, qd4 = lane >> 4;
    const int mh = wv >> 2, nh = wv & 3;
    const int gR0 = tile*64;

    if (tid < 66) {
        int gr = gR0 + tid;
        int t = -1;
        if (gr < 32768) {
            int b = gr >> 8, pos = gr & 255;
            if (pos < Dn) t = dtok[b*Dn + pos];
            else if (pos >= 208 && pos < 238) t = qtok[b*Qn + (pos - 208)];
        }
        toks[tid] = t;
    }
    __syncthreads();

    // issue ks0 weight DMA (6 chunks/wave) — flies during the whole gather
    {
        const char* src = (const char*)Wt3 + lane*16;
        #pragma unroll
        for (int i = 0; i < 6; ++i) {
            int chunk = wv*6 + i;
            gld_lds16(src + chunk*1024, Bs0 + chunk*1024);
        }
    }
    // gather A: 66 rows x 80 col4 (cols >= 75 and masked rows -> zero;
    // K cols 300..319 MUST be zero since W is zero there but 0*NaN != 0)
    #pragma unroll
    for (int i = 0; i < 11; ++i) {
        int idx = tid + i*512;
        if (idx < 5280) {
            int r = idx / 80, c4 = idx - r*80;
            int t = toks[r];
            u16 o0=0,o1=0,o2=0,o3=0;
            if (t >= 0 && c4 < 75) {
                float4 v = *(const float4*)(emb + t*En + c4*4);
                o0=f2b(v.x); o1=f2b(v.y); o2=f2b(v.z); o3=f2b(v.w);
            }
            u16* pdst = (u16*)(As + r*656 + c4*8);
            pdst[0]=o0; pdst[1]=o1; pdst[2]=o2; pdst[3]=o3;
        }
    }

    float bias[3][2];
    #pragma unroll
    for (int nt = 0; nt < 2; ++nt) {
        int ch = nh*32 + nt*16 + l15;
        bias[0][nt] = b1[ch];
        bias[1][nt] = b2[ch];
        bias[2][nt] = b3[ch];
    }

    floatx4 acc[3][2][2];
    #pragma unroll
    for (int g = 0; g < 3; ++g)
        #pragma unroll
        for (int mt = 0; mt < 2; ++mt)
            #pragma unroll
            for (int nt = 0; nt < 2; ++nt)
                acc[g][mt][nt] = (floatx4){0.f,0.f,0.f,0.f};

    // prologue drain: A gather (lgkm) + ks0 DMA (vmcnt) complete, all waves
    asm volatile("s_waitcnt vmcnt(0) lgkmcnt(0)" ::: "memory");
    __builtin_amdgcn_s_barrier();

    #pragma unroll 1
    for (int ks = 0; ks < 10; ++ks) {
        char* Bcur = (ks & 1) ? Bs1 : Bs0;
        char* Bnxt = (ks & 1) ? Bs0 : Bs1;
        if (ks < 9) {                       // issue ks+1 DMA; flies under MFMAs
            const char* src = (const char*)Wt3 + (ks+1)*49152 + lane*16;
            #pragma unroll
            for (int i = 0; i < 6; ++i) {
                int chunk = wv*6 + i;
                gld_lds16(src + chunk*1024, Bnxt + chunk*1024);
            }
        }
        short8 af[2][3];
        #pragma unroll
        for (int mt = 0; mt < 2; ++mt)
            #pragma unroll
            for (int j = 0; j < 3; ++j)
                af[mt][j] = *(const short8*)(As + (mh*32 + mt*16 + l15 + j)*656 + ks*64 + qd4*16);
        #pragma unroll
        for (int g = 0; g < 3; ++g) {
            const int cbB = (g == 0) ? 0 : (g == 1) ? 8192 : 24576;  // bytes
            #pragma unroll
            for (int j = 0; j <= g; ++j) {
                const char* bb = Bcur + cbB + (j*8 + nh*2)*1024 + lane*16;
                short8 w0  = *(const short8*)(bb);
                short8 w1v = *(const short8*)(bb + 1024);
                #pragma unroll
                for (int mt = 0; mt < 2; ++mt) {
                    acc[g][mt][0] = __builtin_amdgcn_mfma_f32_16x16x32_bf16(
                        af[mt][j], w0,  acc[g][mt][0], 0, 0, 0);
                    acc[g][mt][1] = __builtin_amdgcn_mfma_f32_16x16x32_bf16(
                        af[mt][j], w1v, acc[g][mt][1], 0, 0, 0);
                }
            }
        }
        // drain the ks+1 DMA remainder (it had the whole compute to land)
        asm volatile("s_waitcnt vmcnt(0)" ::: "memory");
        __builtin_amdgcn_s_barrier();
    }

    // epilogue: per-gram Gs overlay on As; fully unrolled over g (rule #20);
    // norms across all 512 threads (8 lanes/row + shfl_xor).
    u16* Gs = (u16*)smem;                   // [64][136]
    #pragma unroll
    for (int g = 0; g < 3; ++g) {
        __syncthreads();
        #pragma unroll
        for (int mt = 0; mt < 2; ++mt)
            #pragma unroll
            for (int nt = 0; nt < 2; ++nt) {
                int ch = nh*32 + nt*16 + l15;
                #pragma unroll
                for (int i = 0; i < 4; ++i) {
                    int row = mh*32 + mt*16 + qd4*4 + i;
                    Gs[row*136 + ch] = f2b(fmaxf(acc[g][mt][nt][i] + bias[g][nt], 0.f));
                }
            }
        __syncthreads();

        {
            int r = tid >> 3, pp = tid & 7;
            const char* rp = (const char*)Gs + r*272 + pp*32;
            float ssum = 0.f;
            #pragma unroll
            for (int t2 = 0; t2 < 2; ++t2) {
                uint4 u = *(const uint4*)(rp + t2*16);
                float x;
                x = bits2f(u.x << 16); ssum += x*x;  x = bits2f(u.x & 0xffff0000u); ssum += x*x;
                x = bits2f(u.y << 16); ssum += x*x;  x = bits2f(u.y & 0xffff0000u); ssum += x*x;
                x = bits2f(u.z << 16); ssum += x*x;  x = bits2f(u.z & 0xffff0000u); ssum += x*x;
                x = bits2f(u.w << 16); ssum += x*x;  x = bits2f(u.w & 0xffff0000u); ssum += x*x;
            }
            ssum += __shfl_xor(ssum, 1);
            ssum += __shfl_xor(ssum, 2);
            ssum += __shfl_xor(ssum, 4);
            if (pp == 0) {
                float inv = 1.f / (sqrtf(ssum) + 1e-13f);
                int gr = gR0 + r;
                int b = gr >> 8, pos = gr & 255;
                if (pos < 208)      invnd[(g*B_ + b)*208 + pos] = inv;
                else if (pos < 238) invnq[(g*B_ + b)*32 + (pos - 208)] = inv;
            }
        }
        #pragma unroll
        for (int i = 0; i < 2; ++i) {
            int idx = tid + i*512;
            int r = idx >> 4, c16 = idx & 15;
            uint4 v = *(const uint4*)((const char*)Gs + r*272 + c16*16);
            int gr = gR0 + r;
            int b = gr >> 8, pos = gr & 255;
            if (pos < 208)      *(uint4*)(dg + ((g*B_ + b)*208 + pos)*128 + c16*8) = v;
            else if (pos < 238) *(uint4*)(qg + ((g*B_ + b)*32 + (pos - 208))*128 + c16*8) = v;
        }
    }
}

// ---------------------------------------------------------------------------
// Pool: R3-EXACT (best measured pool: 33 us). Block per (dj,b), 256 thr,
// qi-outer with hoisted qf, t-loop (3-4 tiles/wave) pipelines the exp chain.
// R5-R7's "more TLP / fewer tiles per wave" variants all regressed (42/47/53).
// ---------------------------------------------------------------------------
__global__ __launch_bounds__(256, 2) void pool_kernel(
    const u16* __restrict__ qg, const u16* __restrict__ dg,
    const float* __restrict__ invnq, const float* __restrict__ invnd,
    const int* __restrict__ qtok, const int* __restrict__ dtok,
    float* __restrict__ feats)
{
    __shared__ __align__(16) u16 dsb[208*136];     // 56576 B
    __shared__ float pk[96*12];                    // 4608 B
    __shared__ float invqA[96];
    __shared__ float qmA[96];
    __shared__ __align__(16) float invd[208];

    const int tid = threadIdx.x;
    const int b = blockIdx.y, dj = blockIdx.x;
    const int wv = tid >> 6, lane = tid & 63;
    const int l15 = lane & 15, qd4 = lane >> 4;

    for (int idx = tid; idx < 208*16; idx += 256) {
        int r = idx >> 4, ch = idx & 15;
        uint4 v = make_uint4(0u,0u,0u,0u);
        if (r < Dn) v = *(const uint4*)(dg + ((dj*B_ + b)*208 + r)*128 + ch*8);
        *(uint4*)((char*)dsb + r*272 + ch*16) = v;
    }
    if (tid < 208) {
        float v = invnd[(dj*B_ + b)*208 + tid];
        bool ok = (tid < Dn) && (dtok[b*Dn + tid] > 0);
        invd[tid] = ok ? v : (-fabsf(v) - 1.0f);   // strictly negative if masked
    }
    if (tid < 96) {
        int qi = tid >> 5, qr = tid & 31;
        float v = invnq[(qi*B_ + b)*32 + qr];
        bool ok = (qr < Qn) && (qtok[b*Qn + qr] > 0);
        invqA[tid] = ok ? v : 0.f;
        qmA[tid] = ok ? 1.f : 0.f;
    }
    for (int i = tid; i < 96*12; i += 256) pk[i] = 0.f;
    __syncthreads();

    // chain constants C_k = exp(10*(mu_k + mu_{k+1})), mu: 0.9,0.7,...,-0.9
    const float CkR[9] = {8886110.5f, 162754.79f, 2980.958f, 54.598150f, 1.0f,
                          0.018315639f, 3.3546263e-4f, 6.1442124e-6f, 1.1253517e-7f};

    for (int qi = 0; qi < 3; ++qi) {
        short8 qf[2][4];
        float vq[2];
        #pragma unroll
        for (int qt = 0; qt < 2; ++qt) {
            vq[qt] = invqA[qi*32 + qt*16 + l15];
            #pragma unroll
            for (int ks = 0; ks < 4; ++ks)
                qf[qt][ks] = *(const short8*)(qg + ((qi*B_ + b)*32 + qt*16 + l15)*128 + ks*32 + qd4*8);
        }
        float pkl[2][11];
        #pragma unroll
        for (int qt = 0; qt < 2; ++qt)
            #pragma unroll
            for (int k = 0; k < 11; ++k) pkl[qt][k] = 0.f;

        for (int t = wv; t < 13; t += 4) {
            short8 af[4];
            #pragma unroll
            for (int ks = 0; ks < 4; ++ks)
                af[ks] = *(const short8*)((const char*)dsb + (t*16 + l15)*272 + ks*64 + qd4*16);
            floatx4 acc[2];
            acc[0] = (floatx4){0.f,0.f,0.f,0.f};
            acc[1] = (floatx4){0.f,0.f,0.f,0.f};
            #pragma unroll
            for (int ks = 0; ks < 4; ++ks)
                #pragma unroll
                for (int qt = 0; qt < 2; ++qt)
                    acc[qt] = __builtin_amdgcn_mfma_f32_16x16x32_bf16(af[ks], qf[qt][ks], acc[qt], 0, 0, 0);
            floatx4 iv4 = *(const floatx4*)(invd + t*16 + qd4*4);
            #pragma unroll
            for (int qt = 0; qt < 2; ++qt)
                #pragma unroll
                for (int i = 0; i < 4; ++i) {
                    float cs = acc[qt][i] * vq[qt] * iv4[i];
                    cs = (cs > 0.f) ? cs : 2.0f;   // masked/zero -> all kernels ~0
                    float t0 = cs - 1.0f;
                    float u  = cs - 0.9f;
                    float s0 = __expf(-500000.f * t0 * t0);
                    float e  = __expf(-50.f * u * u);
                    float rr = __expf(-20.f * cs);
                    pkl[qt][0] += s0;
                    pkl[qt][1] += e;
                    #pragma unroll
                    for (int kk = 0; kk < 9; ++kk) {
                        e = e * rr * CkR[kk];
                        pkl[qt][2 + kk] += e;
                    }
                }
        }
        #pragma unroll
        for (int qt = 0; qt < 2; ++qt)
            #pragma unroll
            for (int k = 0; k < 11; ++k) {
                float v = pkl[qt][k];
                v += __shfl_xor(v, 16);
                v += __shfl_xor(v, 32);
                if (qd4 == 0) atomicAdd(&pk[(qi*32 + qt*16 + l15)*12 + k], v);
            }
    }
    __syncthreads();

    if (tid < 33) {
        int qi = tid / 11, k = tid - qi*11;
        float s = 0.f;
        for (int q = 0; q < Qn; ++q)
            s += qmA[qi*32 + q] * 0.01f * __logf(fmaxf(pk[(qi*32 + q)*12 + k], 1e-10f));
        feats[(b*9 + qi*3 + dj)*11 + k] = s;
    }
}

// ---------------------------------------------------------------------------
__global__ void final_kernel(const float* __restrict__ feats,
                             const float* __restrict__ dw,
                             float* __restrict__ out) {
    int b = threadIdx.x;
    if (b < B_) {
        float s = 0.f;
        for (int f = 0; f < 99; ++f) s += feats[b*99 + f] * dw[f];
        out[b] = s;
    }
}

extern "C" void kernel_launch(void* const* d_in, const int* in_sizes, int n_in,
                              void* d_out, int out_size, void* d_ws, size_t ws_size,
                              hipStream_t stream) {
    const int*   qtok = (const int*)d_in[0];
    const int*   dtok = (const int*)d_in[1];
    const float* emb  = (const float*)d_in[2];
    const float* w1   = (const float*)d_in[3];
    const float* w2   = (const float*)d_in[4];
    const float* w3   = (const float*)d_in[5];
    const float* b1   = (const float*)d_in[6];
    const float* b2   = (const float*)d_in[7];
    const float* b3   = (const float*)d_in[8];
    const float* dw   = (const float*)d_in[9];
    float* out = (float*)d_out;

    char* w = (char*)d_ws;
    u16*   Wt3   = (u16*)w;                      // 491,520 B
    u16*   qg    = (u16*)(w + 491520);           // 3*128*32*128*2  = 3,145,728
    u16*   dgm   = (u16*)(w + 3637248);          // 3*128*208*128*2 = 20,447,232
    float* invq_ = (float*)(w + 24084480);       // 49,152
    float* invd_ = (float*)(w + 24133632);       // 319,488
    float* feats = (float*)(w + 24453120);       // 50,688 -> total 24,503,808

    prep_kernel<<<dim3(8, B_), 256, 0, stream>>>(w1, w2, w3, Wt3);

    const int conv_lds = 141864;                 // As+toks + 2x48K B dbuf
    hipFuncSetAttribute(reinterpret_cast<const void*>(conv_kernel),
                        hipFuncAttributeMaxDynamicSharedMemorySize, conv_lds);
    conv_kernel<<<dim3(512), 512, conv_lds, stream>>>(
        qtok, dtok, emb, Wt3, b1, b2, b3, qg, dgm, invq_, invd_);

    pool_kernel<<<dim3(3, B_), 256, 0, stream>>>(qg, dgm, invq_, invd_, qtok, dtok, feats);

    final_kernel<<<1, 128, 0, stream>>>(feats, dw, out);
}

// Round 9
// 161.561 us; speedup vs baseline: 1.3526x; 1.3526x over previous
//
#include <hip/hip_runtime.h>
#include <hip/hip_bf16.h>
#include <math.h>

#define B_   128
#define Qn   30
#define Dn   200
#define En   300

typedef __attribute__((ext_vector_type(8))) short short8;
typedef __attribute__((ext_vector_type(4))) float floatx4;
typedef unsigned int u32;
typedef unsigned short u16;

static __device__ __forceinline__ u16 f2b(float x) {   // fp32 -> bf16 RNE
    union { float f; u32 u; } v; v.f = x;
    u32 r = v.u + 0x7FFFu + ((v.u >> 16) & 1u);
    return (u16)(r >> 16);
}
static __device__ __forceinline__ float bits2f(u32 u) {
    union { u32 u2; float f; } v; v.u2 = u; return v.f;
}

// ---------------------------------------------------------------------------
// prep: weight permute ONLY. ks-major: one K-slice = contiguous 48 KB:
//   Wt3[ks 10][ g1 j0 (8 chunks) | g2 j0,j1 (16) | g3 j0..j2 (24) ] x 1KB
// ---------------------------------------------------------------------------
__global__ void prep_kernel(
    const float* __restrict__ w1, const float* __restrict__ w2, const float* __restrict__ w3,
    u16* __restrict__ Wt3)
{
    int p = (blockIdx.x*128 + blockIdx.y)*256 + threadIdx.x;
    if (p >= 245760) return;
    int ks = p / 24576;
    int r  = p - ks*24576;
    int g, rr;
    if (r < 4096)        { g = 0; rr = r;         }
    else if (r < 12288)  { g = 1; rr = r - 4096;  }
    else                 { g = 2; rr = r - 12288; }
    int j  = rr >> 12;
    int r2 = rr & 4095;
    int nt  = r2 >> 9;
    int q4  = (r2 >> 7) & 3;
    int c16 = (r2 >> 3) & 15;
    int k8  = r2 & 7;
    int ch = nt*16 + c16;
    int e  = ks*32 + q4*8 + k8;
    float v = 0.f;
    if (e < En) {
        if (g == 0)      v = w1[ch*En + e];
        else if (g == 1) v = w2[(ch*En + e)*2 + j];
        else             v = w3[(ch*En + e)*3 + j];
    }
    Wt3[p] = f2b(v);
}

// ---------------------------------------------------------------------------
// Fused conv (R4 structure, banked: ~35 us, best of R1/R3/R4/R8 variants).
// B register-direct from L2-resident Wt3; no K-loop barriers; split A-gather
// with issue-early K-hi registers; 512-thread epilogue norms.
// ---------------------------------------------------------------------------
__global__ __launch_bounds__(512, 4) void conv_kernel(
    const int* __restrict__ qtok, const int* __restrict__ dtok,
    const float* __restrict__ emb,
    const u16* __restrict__ Wt3,
    const float* __restrict__ b1, const float* __restrict__ b2, const float* __restrict__ b3,
    u16* __restrict__ qg, u16* __restrict__ dg,
    float* __restrict__ invnq, float* __restrict__ invnd)
{
    __shared__ __align__(16) char smem[43560];   // As [66][656] + toks[66]
    char* As  = smem;
    int*  toks = (int*)(smem + 43296);

    const int tile = blockIdx.x;
    const int tid = threadIdx.x;
    const int wv = tid >> 6, lane = tid & 63;
    const int l15 = lane & 15, qd4 = lane >> 4;
    const int mh = wv >> 2, nh = wv & 3;
    const int gR0 = tile*64;

    if (tid < 66) {
        int gr = gR0 + tid;
        int t = -1;
        if (gr < 32768) {
            int b = gr >> 8, pos = gr & 255;
            if (pos < Dn) t = dtok[b*Dn + pos];
            else if (pos >= 208 && pos < 238) t = qtok[b*Qn + (pos - 208)];
        }
        toks[tid] = t;
    }
    __syncthreads();

    #pragma unroll
    for (int i = 0; i < 6; ++i) {
        int idx = tid + i*512;
        if (idx < 2640) {
            int r = idx / 40, c4 = idx - r*40;
            int t = toks[r];
            u16 o0=0,o1=0,o2=0,o3=0;
            if (t >= 0) {
                float4 v = *(const float4*)(emb + t*En + c4*4);
                o0=f2b(v.x); o1=f2b(v.y); o2=f2b(v.z); o3=f2b(v.w);
            }
            u16* pdst = (u16*)(As + r*656 + c4*8);
            pdst[0]=o0; pdst[1]=o1; pdst[2]=o2; pdst[3]=o3;
        }
    }

    float bias[3][2];
    #pragma unroll
    for (int nt = 0; nt < 2; ++nt) {
        int ch = nh*32 + nt*16 + l15;
        bias[0][nt] = b1[ch];
        bias[1][nt] = b2[ch];
        bias[2][nt] = b3[ch];
    }

    floatx4 acc[3][2][2];
    #pragma unroll
    for (int g = 0; g < 3; ++g)
        #pragma unroll
        for (int mt = 0; mt < 2; ++mt)
            #pragma unroll
            for (int nt = 0; nt < 2; ++nt)
                acc[g][mt][nt] = (floatx4){0.f,0.f,0.f,0.f};

    __syncthreads();                        // A K-lo ready

    float4 hf[6];
    #pragma unroll
    for (int i = 0; i < 6; ++i) {
        int idx = tid + i*512;
        const float* p = emb;               // safe dummy
        if (idx < 2640) {
            int r = idx / 40, c = idx - r*40;
            int t = toks[r];
            if (t >= 0 && c < 35) p = emb + t*En + (40 + c)*4;
        }
        hf[i] = *(const float4*)p;
    }

    #pragma unroll 1
    for (int ks = 0; ks < 5; ++ks) {
        short8 af[2][3];
        #pragma unroll
        for (int mt = 0; mt < 2; ++mt)
            #pragma unroll
            for (int j = 0; j < 3; ++j)
                af[mt][j] = *(const short8*)(As + (mh*32 + mt*16 + l15 + j)*656 + ks*64 + qd4*16);
        const u16* Wks = Wt3 + ks*24576;
        #pragma unroll
        for (int g = 0; g < 3; ++g) {
            const int cbW = (g == 0) ? 0 : (g == 1) ? 4096 : 12288;
            #pragma unroll
            for (int j = 0; j <= g; ++j) {
                const u16* bb = Wks + cbW + (j*8 + nh*2)*512 + lane*8;
                short8 w0  = *(const short8*)(bb);
                short8 w1v = *(const short8*)(bb + 512);
                #pragma unroll
                for (int mt = 0; mt < 2; ++mt) {
                    acc[g][mt][0] = __builtin_amdgcn_mfma_f32_16x16x32_bf16(
                        af[mt][j], w0,  acc[g][mt][0], 0, 0, 0);
                    acc[g][mt][1] = __builtin_amdgcn_mfma_f32_16x16x32_bf16(
                        af[mt][j], w1v, acc[g][mt][1], 0, 0, 0);
                }
            }
        }
    }

    #pragma unroll
    for (int i = 0; i < 6; ++i) {
        int idx = tid + i*512;
        if (idx < 2640) {
            int r = idx / 40, c = idx - r*40;
            int t = toks[r];
            bool ok = (t >= 0) && (c < 35);
            u16 o0=0,o1=0,o2=0,o3=0;
            if (ok) { o0=f2b(hf[i].x); o1=f2b(hf[i].y); o2=f2b(hf[i].z); o3=f2b(hf[i].w); }
            u16* pdst = (u16*)(As + r*656 + (40 + c)*8);
            pdst[0]=o0; pdst[1]=o1; pdst[2]=o2; pdst[3]=o3;
        }
    }
    __syncthreads();                        // K-hi ready

    #pragma unroll 1
    for (int ks = 5; ks < 10; ++ks) {
        short8 af[2][3];
        #pragma unroll
        for (int mt = 0; mt < 2; ++mt)
            #pragma unroll
            for (int j = 0; j < 3; ++j)
                af[mt][j] = *(const short8*)(As + (mh*32 + mt*16 + l15 + j)*656 + ks*64 + qd4*16);
        const u16* Wks = Wt3 + ks*24576;
        #pragma unroll
        for (int g = 0; g < 3; ++g) {
            const int cbW = (g == 0) ? 0 : (g == 1) ? 4096 : 12288;
            #pragma unroll
            for (int j = 0; j <= g; ++j) {
                const u16* bb = Wks + cbW + (j*8 + nh*2)*512 + lane*8;
                short8 w0  = *(const short8*)(bb);
                short8 w1v = *(const short8*)(bb + 512);
                #pragma unroll
                for (int mt = 0; mt < 2; ++mt) {
                    acc[g][mt][0] = __builtin_amdgcn_mfma_f32_16x16x32_bf16(
                        af[mt][j], w0,  acc[g][mt][0], 0, 0, 0);
                    acc[g][mt][1] = __builtin_amdgcn_mfma_f32_16x16x32_bf16(
                        af[mt][j], w1v, acc[g][mt][1], 0, 0, 0);
                }
            }
        }
    }

    u16* Gs = (u16*)smem;                   // [64][136]
    #pragma unroll
    for (int g = 0; g < 3; ++g) {
        __syncthreads();
        #pragma unroll
        for (int mt = 0; mt < 2; ++mt)
            #pragma unroll
            for (int nt = 0; nt < 2; ++nt) {
                int ch = nh*32 + nt*16 + l15;
                #pragma unroll
                for (int i = 0; i < 4; ++i) {
                    int row = mh*32 + mt*16 + qd4*4 + i;
                    Gs[row*136 + ch] = f2b(fmaxf(acc[g][mt][nt][i] + bias[g][nt], 0.f));
                }
            }
        __syncthreads();

        {
            int r = tid >> 3, pp = tid & 7;
            const char* rp = (const char*)Gs + r*272 + pp*32;
            float ssum = 0.f;
            #pragma unroll
            for (int t2 = 0; t2 < 2; ++t2) {
                uint4 u = *(const uint4*)(rp + t2*16);
                float x;
                x = bits2f(u.x << 16); ssum += x*x;  x = bits2f(u.x & 0xffff0000u); ssum += x*x;
                x = bits2f(u.y << 16); ssum += x*x;  x = bits2f(u.y & 0xffff0000u); ssum += x*x;
                x = bits2f(u.z << 16); ssum += x*x;  x = bits2f(u.z & 0xffff0000u); ssum += x*x;
                x = bits2f(u.w << 16); ssum += x*x;  x = bits2f(u.w & 0xffff0000u); ssum += x*x;
            }
            ssum += __shfl_xor(ssum, 1);
            ssum += __shfl_xor(ssum, 2);
            ssum += __shfl_xor(ssum, 4);
            if (pp == 0) {
                float inv = 1.f / (sqrtf(ssum) + 1e-13f);
                int gr = gR0 + r;
                int b = gr >> 8, pos = gr & 255;
                if (pos < 208)      invnd[(g*B_ + b)*208 + pos] = inv;
                else if (pos < 238) invnq[(g*B_ + b)*32 + (pos - 208)] = inv;
            }
        }
        #pragma unroll
        for (int i = 0; i < 2; ++i) {
            int idx = tid + i*512;
            int r = idx >> 4, c16 = idx & 15;
            uint4 v = *(const uint4*)((const char*)Gs + r*272 + c16*16);
            int gr = gR0 + r;
            int b = gr >> 8, pos = gr & 255;
            if (pos < 208)      *(uint4*)(dg + ((g*B_ + b)*208 + pos)*128 + c16*8) = v;
            else if (pos < 238) *(uint4*)(qg + ((g*B_ + b)*32 + (pos - 208))*128 + c16*8) = v;
        }
    }
}

// ---------------------------------------------------------------------------
// Pool, R9: R3 body EXACTLY (qi-loop body, hoisted qf, t=wv..13 step 4 —
// the only pool structure that ever performed), but grid split by qi:
// (3 dj, 128 b, 3 qi) = 1152 blocks -> 4.5 waves/SIMD (vs R3's 1.5).
// d-LDS staging DROPPED: af reads straight from L2-hot dg (53 KB/block;
// lesson #7 — don't stage what L2 fits). Bit-exact: ReLU => dg,qg >= 0 =>
// acc >= 0; masked rows have invd < 0 => cs <= 0 => same 2.0 path as R3's
// zeroed rows. Per-wave tile partition and reduce order unchanged.
// ---------------------------------------------------------------------------
__global__ __launch_bounds__(256, 4) void pool_kernel(
    const u16* __restrict__ qg, const u16* __restrict__ dg,
    const float* __restrict__ invnq, const float* __restrict__ invnd,
    const int* __restrict__ qtok, const int* __restrict__ dtok,
    float* __restrict__ feats)
{
    __shared__ float pk[32*12];                    // 1536 B
    __shared__ float invqA[32];
    __shared__ float qmA[32];
    __shared__ __align__(16) float invd[208];

    const int tid = threadIdx.x;
    const int b = blockIdx.y, dj = blockIdx.x, qi = blockIdx.z;
    const int wv = tid >> 6, lane = tid & 63;
    const int l15 = lane & 15, qd4 = lane >> 4;

    if (tid < 208) {
        float v = invnd[(dj*B_ + b)*208 + tid];
        bool ok = (tid < Dn) && (dtok[b*Dn + tid] > 0);
        invd[tid] = ok ? v : (-fabsf(v) - 1.0f);   // strictly negative if masked
    }
    if (tid < 32) {
        float v = invnq[(qi*B_ + b)*32 + tid];
        bool ok = (tid < Qn) && (qtok[b*Qn + tid] > 0);
        invqA[tid] = ok ? v : 0.f;
        qmA[tid] = ok ? 1.f : 0.f;
    }
    for (int i = tid; i < 32*12; i += 256) pk[i] = 0.f;
    __syncthreads();

    // chain constants C_k = exp(10*(mu_k + mu_{k+1})), mu: 0.9,0.7,...,-0.9
    const float CkR[9] = {8886110.5f, 162754.79f, 2980.958f, 54.598150f, 1.0f,
                          0.018315639f, 3.3546263e-4f, 6.1442124e-6f, 1.1253517e-7f};

    {
        short8 qf[2][4];
        float vq[2];
        #pragma unroll
        for (int qt = 0; qt < 2; ++qt) {
            vq[qt] = invqA[qt*16 + l15];
            #pragma unroll
            for (int ks = 0; ks < 4; ++ks)
                qf[qt][ks] = *(const short8*)(qg + ((qi*B_ + b)*32 + qt*16 + l15)*128 + ks*32 + qd4*8);
        }
        float pkl[2][11];
        #pragma unroll
        for (int qt = 0; qt < 2; ++qt)
            #pragma unroll
            for (int k = 0; k < 11; ++k) pkl[qt][k] = 0.f;

        const u16* dbase = dg + (size_t)(dj*B_ + b)*208*128;
        for (int t = wv; t < 13; t += 4) {
            short8 af[4];
            #pragma unroll
            for (int ks = 0; ks < 4; ++ks)
                af[ks] = *(const short8*)(dbase + (t*16 + l15)*128 + ks*32 + qd4*8);
            floatx4 acc[2];
            acc[0] = (floatx4){0.f,0.f,0.f,0.f};
            acc[1] = (floatx4){0.f,0.f,0.f,0.f};
            #pragma unroll
            for (int ks = 0; ks < 4; ++ks)
                #pragma unroll
                for (int qt = 0; qt < 2; ++qt)
                    acc[qt] = __builtin_amdgcn_mfma_f32_16x16x32_bf16(af[ks], qf[qt][ks], acc[qt], 0, 0, 0);
            floatx4 iv4 = *(const floatx4*)(invd + t*16 + qd4*4);
            #pragma unroll
            for (int qt = 0; qt < 2; ++qt)
                #pragma unroll
                for (int i = 0; i < 4; ++i) {
                    float cs = acc[qt][i] * vq[qt] * iv4[i];
                    cs = (cs > 0.f) ? cs : 2.0f;   // masked/zero -> all kernels ~0
                    float t0 = cs - 1.0f;
                    float u  = cs - 0.9f;
                    float s0 = __expf(-500000.f * t0 * t0);
                    float e  = __expf(-50.f * u * u);
                    float rr = __expf(-20.f * cs);
                    pkl[qt][0] += s0;
                    pkl[qt][1] += e;
                    #pragma unroll
                    for (int kk = 0; kk < 9; ++kk) {
                        e = e * rr * CkR[kk];
                        pkl[qt][2 + kk] += e;
                    }
                }
        }
        #pragma unroll
        for (int qt = 0; qt < 2; ++qt)
            #pragma unroll
            for (int k = 0; k < 11; ++k) {
                float v = pkl[qt][k];
                v += __shfl_xor(v, 16);
                v += __shfl_xor(v, 32);
                if (qd4 == 0) atomicAdd(&pk[(qt*16 + l15)*12 + k], v);
            }
    }
    __syncthreads();

    if (tid < 11) {
        int k = tid;
        float s = 0.f;
        for (int q = 0; q < Qn; ++q)
            s += qmA[q] * 0.01f * __logf(fmaxf(pk[q*12 + k], 1e-10f));
        feats[(b*9 + qi*3 + dj)*11 + k] = s;
    }
}

// ---------------------------------------------------------------------------
__global__ void final_kernel(const float* __restrict__ feats,
                             const float* __restrict__ dw,
                             float* __restrict__ out) {
    int b = threadIdx.x;
    if (b < B_) {
        float s = 0.f;
        for (int f = 0; f < 99; ++f) s += feats[b*99 + f] * dw[f];
        out[b] = s;
    }
}

extern "C" void kernel_launch(void* const* d_in, const int* in_sizes, int n_in,
                              void* d_out, int out_size, void* d_ws, size_t ws_size,
                              hipStream_t stream) {
    const int*   qtok = (const int*)d_in[0];
    const int*   dtok = (const int*)d_in[1];
    const float* emb  = (const float*)d_in[2];
    const float* w1   = (const float*)d_in[3];
    const float* w2   = (const float*)d_in[4];
    const float* w3   = (const float*)d_in[5];
    const float* b1   = (const float*)d_in[6];
    const float* b2   = (const float*)d_in[7];
    const float* b3   = (const float*)d_in[8];
    const float* dw   = (const float*)d_in[9];
    float* out = (float*)d_out;

    char* w = (char*)d_ws;
    u16*   Wt3   = (u16*)w;                      // 491,520 B
    u16*   qg    = (u16*)(w + 491520);           // 3*128*32*128*2  = 3,145,728
    u16*   dgm   = (u16*)(w + 3637248);          // 3*128*208*128*2 = 20,447,232
    float* invq_ = (float*)(w + 24084480);       // 49,152
    float* invd_ = (float*)(w + 24133632);       // 319,488
    float* feats = (float*)(w + 24453120);       // 50,688 -> total 24,503,808

    prep_kernel<<<dim3(8, B_), 256, 0, stream>>>(w1, w2, w3, Wt3);

    conv_kernel<<<dim3(512), 512, 0, stream>>>(
        qtok, dtok, emb, Wt3, b1, b2, b3, qg, dgm, invq_, invd_);

    pool_kernel<<<dim3(3, B_, 3), 256, 0, stream>>>(qg, dgm, invq_, invd_, qtok, dtok, feats);

    final_kernel<<<1, 128, 0, stream>>>(feats, dw, out);
}